// Round 15
// baseline (31.858 us; speedup 1.0000x reference)
//
#include <hip/hip_runtime.h>
#include <hip/hip_bf16.h>

#define NPIX 65536
#define NB 8
#define NN 64
#define KK 32
#define LOG2E 1.4426950408889634f

typedef __attribute__((ext_vector_type(4))) float f32x4;
typedef __attribute__((ext_vector_type(8))) short bf16x8;

__device__ __forceinline__ float rcpf(float x) { return __builtin_amdgcn_rcpf(x); }
__device__ __forceinline__ float exp2_fast(float x) { float r; asm("v_exp_f32 %0, %1" : "=v"(r) : "v"(x)); return r; }
__device__ __forceinline__ float log2_fast(float x) { float r; asm("v_log_f32 %0, %1" : "=v"(r) : "v"(x)); return r; }
__device__ __forceinline__ short f2bf(float x) {
    union { __hip_bfloat16 b; short s; } u; u.b = __float2bfloat16(x); return u.s;
}

// Phase 1 via MFMA, layout-probed, swapped operands (D rows = n, cols = pixel).
// Block = 256 thr = 4 waves = TWO rows of one batch; wave w owns the (w&1)
// 128-px half of row rp*2+(w>>1) = 8 tiles.
// R15: the 8-tile loop is ROLLED (#pragma unroll 1). VALUBusy fell 60->27%
// as the body was progressively unrolled (R4..R14) -> instruction-fetch-bound
// hypothesis: a ~200-inst loop body stays I$-resident across 8 iters x 4 waves,
// where the ~13KB straight-line body had zero loop-back reuse.
__global__ __launch_bounds__(256) void k_phase1(
    const float* __restrict__ loc,    // [B,N,4]
    const float* __restrict__ masks,  // [B,N,K]
    const float* __restrict__ proto,  // [B,H,W,K]
    const float* __restrict__ conf,   // [B,N]
    float* __restrict__ fcb,          // [B, NPIX]
    float* __restrict__ out)          // zeroed by block 0
{
    __shared__ float4 sprm[2][NN];       // per row: alpha, beta, gamma, pad

    const int b    = blockIdx.x >> 7;    // 8 batches x 128 row-pairs
    const int rp   = blockIdx.x & 127;
    const int tid  = threadIdx.x;
    const int lane = tid & 63;
    const int wave = tid >> 6;
    const int nl   = lane & 15;
    const int kg   = lane >> 4;
    const int rw   = wave >> 1;          // row of the pair (wave-uniform)
    const int half = wave & 1;           // 128-px half    (wave-uniform)
    const int row  = rp * 2 + rw;

    if (blockIdx.x == 0 && tid == 0) *out = 0.0f;   // replaces memset dispatch

    const float inv = 1.0f / 256.0f;

    // ---- issue mask loads FIRST (latency hides under sprm+barrier+probe) ----
    float4 mu0[4], mu1[4];
#pragma unroll
    for (int t = 0; t < 4; ++t) {
        const float* mp = masks + ((size_t)b * NN + 16 * t + nl) * KK + kg * 8;
        mu0[t] = *(const float4*)mp;
        mu1[t] = *(const float4*)(mp + 4);
    }

    // ---- per-(row,n) folded quadratic params ----
    if (tid < 128) {
        const int rr = tid >> 6, n = tid & 63;
        float4 L = ((const float4*)loc)[b * NN + n];
        float isx = rcpf(L.z), isy = rcpf(L.w);
        float gx = -0.72134752f * isx * isx;   // -0.5*log2e/sx^2
        float gy = -0.72134752f * isy * isy;
        float fyr = (rp * 2 + rr + 0.5f) * inv;
        float dy  = fyr - L.y;
        float ey  = fmaf(dy * dy, gy, log2_fast(conf[b * NN + n]));
        float beta  = -2.0f * gx * L.x;
        float gamma = fmaf(gx * L.x, L.x, ey);
        sprm[rr][n] = make_float4(gx, beta, gamma, 0.f);
    }
    __syncthreads();

    // ---- probe: measure (lane,reg) -> (row m, col n) of the MFMA D layout ----
    int mi[4], ni0;
    {
        bf16x8 Ap, Bp;
#pragma unroll
        for (int j = 0; j < 8; ++j) { Ap[j] = 0; Bp[j] = 0; }
        if (kg == 0) {
            Ap[0] = f2bf((float)nl);        // A[m][0] = m
            Ap[1] = f2bf(1.0f);             // A[m][1] = 1
            Bp[0] = f2bf(1.0f);             // B[0][n] = 1
            Bp[1] = f2bf((float)(16 * nl)); // B[1][n] = 16n (exact in bf16)
        }
        f32x4 z = {0.f, 0.f, 0.f, 0.f};
        f32x4 d = __builtin_amdgcn_mfma_f32_16x16x32_bf16(Ap, Bp, z, 0, 0, 0);
#pragma unroll
        for (int r = 0; r < 4; ++r) {
            int v = (int)(d[r] + 0.5f);     // D[m][n] = m + 16n
            mi[r] = v & 15;
            if (r == 0) ni0 = (v >> 4) & 15;
        }
    }

    // ---- mask fragments (first operand): rows n = 16t+nl, k = kg*8+j ----
    bf16x8 Mf[4];
#pragma unroll
    for (int t = 0; t < 4; ++t) {
        bf16x8 v;
        v[0] = f2bf(mu0[t].x * -LOG2E); v[1] = f2bf(mu0[t].y * -LOG2E);
        v[2] = f2bf(mu0[t].z * -LOG2E); v[3] = f2bf(mu0[t].w * -LOG2E);
        v[4] = f2bf(mu1[t].x * -LOG2E); v[5] = f2bf(mu1[t].y * -LOG2E);
        v[6] = f2bf(mu1[t].z * -LOG2E); v[7] = f2bf(mu1[t].w * -LOG2E);
        Mf[t] = v;
    }

    // ---- per-(t,r) quadratic params for this wave's row ----
    float Pa[4][4], Pb[4][4], Pc[4][4];
#pragma unroll
    for (int t = 0; t < 4; ++t)
#pragma unroll
        for (int r = 0; r < 4; ++r) {
            float4 P = sprm[rw][16 * t + mi[r]];
            Pa[t][r] = P.x; Pb[t][r] = P.y; Pc[t][r] = P.z;
        }

    const size_t prow = (size_t)b * NPIX + (size_t)row * 256;
    const int pxb = half * 128;
    const float* pp0 = proto + (prow + pxb + nl) * KK + kg * 8;

    float4 c0 = *(const float4*)(pp0);
    float4 c1 = *(const float4*)(pp0 + 4);

    float fx = (pxb + ni0 + 0.5f) * inv;    // exact dyadic; +1/16 per tile
    const float fxstep = 16.0f * inv;

#pragma unroll 1
    for (int i = 0; i < 8; ++i) {
        // clamped depth-1 prefetch (wave-uniform select; tile 7 reloads itself)
        const float* np = pp0 + (size_t)(i < 7 ? i + 1 : 7) * 512;
        float4 n0 = *(const float4*)np;
        float4 n1 = *(const float4*)(np + 4);

        bf16x8 Pf;
        Pf[0] = f2bf(c0.x); Pf[1] = f2bf(c0.y); Pf[2] = f2bf(c0.z); Pf[3] = f2bf(c0.w);
        Pf[4] = f2bf(c1.x); Pf[5] = f2bf(c1.y); Pf[6] = f2bf(c1.z); Pf[7] = f2bf(c1.w);

        f32x4 z = {0.f, 0.f, 0.f, 0.f};
        f32x4 acc0 = __builtin_amdgcn_mfma_f32_16x16x32_bf16(Mf[0], Pf, z, 0, 0, 0);
        f32x4 acc1 = __builtin_amdgcn_mfma_f32_16x16x32_bf16(Mf[1], Pf, z, 0, 0, 0);
        f32x4 acc2 = __builtin_amdgcn_mfma_f32_16x16x32_bf16(Mf[2], Pf, z, 0, 0, 0);
        f32x4 acc3 = __builtin_amdgcn_mfma_f32_16x16x32_bf16(Mf[3], Pf, z, 0, 0, 0);

        // ---- batched-by-type eval: 32 independent exp2, then 16 rcp ----
        float ge[4][4], us[4][4];
#pragma unroll
        for (int t = 0; t < 4; ++t)
#pragma unroll
            for (int r = 0; r < 4; ++r) {
                float e = fmaf(fmaf(Pa[t][r], fx, Pb[t][r]), fx, Pc[t][r]);
                ge[t][r] = exp2_fast(e);            // conf * gauss
            }
#pragma unroll
        for (int r = 0; r < 4; ++r) us[0][r] = exp2_fast(acc0[r]);
#pragma unroll
        for (int r = 0; r < 4; ++r) us[1][r] = exp2_fast(acc1[r]);
#pragma unroll
        for (int r = 0; r < 4; ++r) us[2][r] = exp2_fast(acc2[r]);
#pragma unroll
        for (int r = 0; r < 4; ++r) us[3][r] = exp2_fast(acc3[r]);

        float s1[4] = {0.f, 0.f, 0.f, 0.f};
        float s2[4] = {0.f, 0.f, 0.f, 0.f};
#pragma unroll
        for (int t = 0; t < 4; ++t)
#pragma unroll
            for (int r = 0; r < 4; ++r) {
                float aa = ge[t][r] * rcpf(1.0f + us[t][r]);
                s1[t] += aa;
                s2[t] = fmaf(aa, aa, s2[t]);
            }
        float S1 = (s1[0] + s1[1]) + (s1[2] + s1[3]);
        float S2 = (s2[0] + s2[1]) + (s2[2] + s2[3]);

        // cross-lane reduce: lanes l, l^16, l^32, l^48 share this pixel
        S1 += __shfl_xor(S1, 16); S1 += __shfl_xor(S1, 32);
        S2 += __shfl_xor(S2, 16); S2 += __shfl_xor(S2, 32);
        if (lane < 16)
            fcb[prow + pxb + i * 16 + ni0] = 1.0f - S2 * rcpf(S1 + 1e-5f);

        c0 = n0; c1 = n1;
        fx += fxstep;
    }
}

// Phase 2: weighted-variance sum -> scalar. One thread = one pixel, all 3
// channels (fcb read once; traffic fcb 2MB + original 6.3MB).
__global__ __launch_bounds__(256) void k_phase2(
    const float* __restrict__ original,  // [B,3,H,W]
    const float* __restrict__ fcb,       // [B, NPIX]
    float* __restrict__ out)
{
    const int pix = blockIdx.x * 256 + threadIdx.x;

    float f[NB];
    float tot = 0.f;
#pragma unroll
    for (int b = 0; b < NB; ++b) { f[b] = fcb[(size_t)b * NPIX + pix]; tot += f[b]; }

    float part = 0.f;
#pragma unroll
    for (int c = 0; c < 3; ++c) {
        float o[NB];
        float wm = 0.f;
#pragma unroll
        for (int b = 0; b < NB; ++b) {
            o[b] = original[((size_t)(b * 3 + c)) * NPIX + pix];
            wm = fmaf(o[b], f[b], wm);
        }
#pragma unroll
        for (int b = 0; b < NB; ++b) {
            float d = o[b] - wm;
            part = fmaf(d * d, f[b], part);
        }
    }
    part *= rcpf(tot);

#pragma unroll
    for (int off = 32; off > 0; off >>= 1) part += __shfl_down(part, off);
    __shared__ float sred[4];
    if ((threadIdx.x & 63) == 0) sred[threadIdx.x >> 6] = part;
    __syncthreads();
    if (threadIdx.x == 0) atomicAdd(out, sred[0] + sred[1] + sred[2] + sred[3]);
}

// Fallback: fully fused scalar path, only if ws_size too small (shouldn't happen).
__global__ __launch_bounds__(256) void k_fused(
    const float* __restrict__ original, const float* __restrict__ loc,
    const float* __restrict__ masks, const float* __restrict__ proto,
    const float* __restrict__ conf, float* __restrict__ out)
{
    const int pix = blockIdx.x * 256 + threadIdx.x;
    const float inv = 1.0f / 256.0f;
    const float fx = ((pix & 255) + 0.5f) * inv;
    const float fy = ((pix >> 8) + 0.5f) * inv;

    float f[NB];
    for (int b = 0; b < NB; ++b) {
        const float4* p4 = (const float4*)(proto + ((size_t)b * NPIX + pix) * KK);
        const float4* m4 = (const float4*)(masks + (size_t)b * NN * KK);
        const float4* l4 = (const float4*)(loc + (size_t)b * NN * 4);
        const float*  cf = conf + b * NN;
        float S1 = 0.f, S2 = 0.f;
        for (int n = 0; n < NN; ++n) {
            float sa = 0.f;
#pragma unroll
            for (int j = 0; j < 8; ++j) {
                float4 A = p4[j], m = m4[n * 8 + j];
                sa = fmaf(A.w, m.w, fmaf(A.z, m.z, fmaf(A.y, m.y, fmaf(A.x, m.x, sa))));
            }
            const float4 L = l4[n];
            float isx = rcpf(L.z), isy = rcpf(L.w);
            float dx = (fx - L.x) * isx, dy = (fy - L.y) * isy;
            float g = __expf(-0.5f * fmaf(dx, dx, dy * dy));
            float a = g * rcpf(1.0f + __expf(-sa)) * cf[n];
            S1 += a;
            S2 = fmaf(a, a, S2);
        }
        f[b] = 1.0f - S2 * rcpf(S1 + 1e-5f);
    }
    float tot = 0.f;
#pragma unroll
    for (int b = 0; b < NB; ++b) tot += f[b];
    float part = 0.f;
#pragma unroll
    for (int c = 0; c < 3; ++c) {
        float o[NB];
        float wm = 0.f;
#pragma unroll
        for (int b = 0; b < NB; ++b) {
            o[b] = original[((size_t)(b * 3 + c)) * NPIX + pix];
            wm = fmaf(o[b], f[b], wm);
        }
#pragma unroll
        for (int b = 0; b < NB; ++b) {
            float d = o[b] - wm;
            part = fmaf(d * d, f[b], part);
        }
    }
    part *= rcpf(tot);

#pragma unroll
    for (int off = 32; off > 0; off >>= 1) part += __shfl_down(part, off);
    __shared__ float sred[4];
    if ((threadIdx.x & 63) == 0) sred[threadIdx.x >> 6] = part;
    __syncthreads();
    if (threadIdx.x == 0) atomicAdd(out, sred[0] + sred[1] + sred[2] + sred[3]);
}

extern "C" void kernel_launch(void* const* d_in, const int* in_sizes, int n_in,
                              void* d_out, int out_size, void* d_ws, size_t ws_size,
                              hipStream_t stream) {
    const float* original = (const float*)d_in[0];
    const float* loc      = (const float*)d_in[1];
    const float* masks    = (const float*)d_in[2];
    const float* proto    = (const float*)d_in[3];
    const float* conf     = (const float*)d_in[4];
    float* out = (float*)d_out;

    const size_t fc_bytes = (size_t)NB * NPIX * sizeof(float);
    if (ws_size >= fc_bytes) {
        float* fcb = (float*)d_ws;
        k_phase1<<<NB * 128, 256, 0, stream>>>(loc, masks, proto, conf, fcb, out);
        k_phase2<<<NPIX / 256, 256, 0, stream>>>(original, fcb, out);
    } else {
        hipMemsetAsync(out, 0, sizeof(float), stream);
        k_fused<<<NPIX / 256, 256, 0, stream>>>(original, loc, masks, proto, conf, out);
    }
}

// Round 16
// 31.169 us; speedup vs baseline: 1.0221x; 1.0221x over previous
//
#include <hip/hip_runtime.h>
#include <hip/hip_bf16.h>

#define NPIX 65536
#define NB 8
#define NN 64
#define KK 32
#define LOG2E 1.4426950408889634f

typedef __attribute__((ext_vector_type(4))) float f32x4;
typedef __attribute__((ext_vector_type(8))) short bf16x8;

__device__ __forceinline__ float rcpf(float x) { return __builtin_amdgcn_rcpf(x); }

// R16: transcendentals as REAL intrinsics, not inline asm. LLVM's scheduler
// treats INLINEASM conservatively (unknown latency, limited reordering) —
// 48 asm trans per tile were pinning the schedule in every prior variant.
#if __has_builtin(__builtin_amdgcn_exp2f)
__device__ __forceinline__ float exp2_fast(float x) { return __builtin_amdgcn_exp2f(x); }
#else
__device__ __forceinline__ float exp2_fast(float x) { float r; asm("v_exp_f32 %0, %1" : "=v"(r) : "v"(x)); return r; }
#endif
#if __has_builtin(__builtin_amdgcn_logf)
__device__ __forceinline__ float log2_fast(float x) { return __builtin_amdgcn_logf(x); }
#else
__device__ __forceinline__ float log2_fast(float x) { float r; asm("v_log_f32 %0, %1" : "=v"(r) : "v"(x)); return r; }
#endif

__device__ __forceinline__ short f2bf(float x) {
    union { __hip_bfloat16 b; short s; } u; u.b = __float2bfloat16(x); return u.s;
}

// Phase 1 via MFMA, layout-probed, swapped operands (D rows = n, cols = pixel).
// Block = 256 thr = 4 waves = TWO rows of one batch; wave w owns the (w&1)
// 128-px half of row rp*2+(w>>1) = 8 tiles. Rolled 8-tile loop (R15).
__global__ __launch_bounds__(256) void k_phase1(
    const float* __restrict__ loc,    // [B,N,4]
    const float* __restrict__ masks,  // [B,N,K]
    const float* __restrict__ proto,  // [B,H,W,K]
    const float* __restrict__ conf,   // [B,N]
    float* __restrict__ fcb,          // [B, NPIX]
    float* __restrict__ out)          // zeroed by block 0
{
    __shared__ float4 sprm[2][NN];       // per row: alpha, beta, gamma, pad

    const int b    = blockIdx.x >> 7;    // 8 batches x 128 row-pairs
    const int rp   = blockIdx.x & 127;
    const int tid  = threadIdx.x;
    const int lane = tid & 63;
    const int wave = tid >> 6;
    const int nl   = lane & 15;
    const int kg   = lane >> 4;
    const int rw   = wave >> 1;          // row of the pair (wave-uniform)
    const int half = wave & 1;           // 128-px half    (wave-uniform)
    const int row  = rp * 2 + rw;

    if (blockIdx.x == 0 && tid == 0) *out = 0.0f;   // replaces memset dispatch

    const float inv = 1.0f / 256.0f;

    // ---- issue mask loads FIRST (latency hides under sprm+barrier+probe) ----
    float4 mu0[4], mu1[4];
#pragma unroll
    for (int t = 0; t < 4; ++t) {
        const float* mp = masks + ((size_t)b * NN + 16 * t + nl) * KK + kg * 8;
        mu0[t] = *(const float4*)mp;
        mu1[t] = *(const float4*)(mp + 4);
    }

    // ---- per-(row,n) folded quadratic params ----
    if (tid < 128) {
        const int rr = tid >> 6, n = tid & 63;
        float4 L = ((const float4*)loc)[b * NN + n];
        float isx = rcpf(L.z), isy = rcpf(L.w);
        float gx = -0.72134752f * isx * isx;   // -0.5*log2e/sx^2
        float gy = -0.72134752f * isy * isy;
        float fyr = (rp * 2 + rr + 0.5f) * inv;
        float dy  = fyr - L.y;
        float ey  = fmaf(dy * dy, gy, log2_fast(conf[b * NN + n]));
        float beta  = -2.0f * gx * L.x;
        float gamma = fmaf(gx * L.x, L.x, ey);
        sprm[rr][n] = make_float4(gx, beta, gamma, 0.f);
    }
    __syncthreads();

    // ---- probe: measure (lane,reg) -> (row m, col n) of the MFMA D layout ----
    int mi[4], ni0;
    {
        bf16x8 Ap, Bp;
#pragma unroll
        for (int j = 0; j < 8; ++j) { Ap[j] = 0; Bp[j] = 0; }
        if (kg == 0) {
            Ap[0] = f2bf((float)nl);        // A[m][0] = m
            Ap[1] = f2bf(1.0f);             // A[m][1] = 1
            Bp[0] = f2bf(1.0f);             // B[0][n] = 1
            Bp[1] = f2bf((float)(16 * nl)); // B[1][n] = 16n (exact in bf16)
        }
        f32x4 z = {0.f, 0.f, 0.f, 0.f};
        f32x4 d = __builtin_amdgcn_mfma_f32_16x16x32_bf16(Ap, Bp, z, 0, 0, 0);
#pragma unroll
        for (int r = 0; r < 4; ++r) {
            int v = (int)(d[r] + 0.5f);     // D[m][n] = m + 16n
            mi[r] = v & 15;
            if (r == 0) ni0 = (v >> 4) & 15;
        }
    }

    // ---- mask fragments (first operand): rows n = 16t+nl, k = kg*8+j ----
    bf16x8 Mf[4];
#pragma unroll
    for (int t = 0; t < 4; ++t) {
        bf16x8 v;
        v[0] = f2bf(mu0[t].x * -LOG2E); v[1] = f2bf(mu0[t].y * -LOG2E);
        v[2] = f2bf(mu0[t].z * -LOG2E); v[3] = f2bf(mu0[t].w * -LOG2E);
        v[4] = f2bf(mu1[t].x * -LOG2E); v[5] = f2bf(mu1[t].y * -LOG2E);
        v[6] = f2bf(mu1[t].z * -LOG2E); v[7] = f2bf(mu1[t].w * -LOG2E);
        Mf[t] = v;
    }

    // ---- per-(t,r) quadratic params for this wave's row ----
    float Pa[4][4], Pb[4][4], Pc[4][4];
#pragma unroll
    for (int t = 0; t < 4; ++t)
#pragma unroll
        for (int r = 0; r < 4; ++r) {
            float4 P = sprm[rw][16 * t + mi[r]];
            Pa[t][r] = P.x; Pb[t][r] = P.y; Pc[t][r] = P.z;
        }

    const size_t prow = (size_t)b * NPIX + (size_t)row * 256;
    const int pxb = half * 128;
    const float* pp0 = proto + (prow + pxb + nl) * KK + kg * 8;

    float4 c0 = *(const float4*)(pp0);
    float4 c1 = *(const float4*)(pp0 + 4);

    float fx = (pxb + ni0 + 0.5f) * inv;    // exact dyadic; +1/16 per tile
    const float fxstep = 16.0f * inv;

#pragma unroll 1
    for (int i = 0; i < 8; ++i) {
        // clamped depth-1 prefetch (wave-uniform select; tile 7 reloads itself)
        const float* np = pp0 + (size_t)(i < 7 ? i + 1 : 7) * 512;
        float4 n0 = *(const float4*)np;
        float4 n1 = *(const float4*)(np + 4);

        bf16x8 Pf;
        Pf[0] = f2bf(c0.x); Pf[1] = f2bf(c0.y); Pf[2] = f2bf(c0.z); Pf[3] = f2bf(c0.w);
        Pf[4] = f2bf(c1.x); Pf[5] = f2bf(c1.y); Pf[6] = f2bf(c1.z); Pf[7] = f2bf(c1.w);

        f32x4 z = {0.f, 0.f, 0.f, 0.f};
        f32x4 acc0 = __builtin_amdgcn_mfma_f32_16x16x32_bf16(Mf[0], Pf, z, 0, 0, 0);
        f32x4 acc1 = __builtin_amdgcn_mfma_f32_16x16x32_bf16(Mf[1], Pf, z, 0, 0, 0);
        f32x4 acc2 = __builtin_amdgcn_mfma_f32_16x16x32_bf16(Mf[2], Pf, z, 0, 0, 0);
        f32x4 acc3 = __builtin_amdgcn_mfma_f32_16x16x32_bf16(Mf[3], Pf, z, 0, 0, 0);

        // ---- batched-by-type eval: 32 independent exp2, then 16 rcp ----
        float ge[4][4], us[4][4];
#pragma unroll
        for (int t = 0; t < 4; ++t)
#pragma unroll
            for (int r = 0; r < 4; ++r) {
                float e = fmaf(fmaf(Pa[t][r], fx, Pb[t][r]), fx, Pc[t][r]);
                ge[t][r] = exp2_fast(e);            // conf * gauss
            }
#pragma unroll
        for (int r = 0; r < 4; ++r) us[0][r] = exp2_fast(acc0[r]);
#pragma unroll
        for (int r = 0; r < 4; ++r) us[1][r] = exp2_fast(acc1[r]);
#pragma unroll
        for (int r = 0; r < 4; ++r) us[2][r] = exp2_fast(acc2[r]);
#pragma unroll
        for (int r = 0; r < 4; ++r) us[3][r] = exp2_fast(acc3[r]);

        float s1[4] = {0.f, 0.f, 0.f, 0.f};
        float s2[4] = {0.f, 0.f, 0.f, 0.f};
#pragma unroll
        for (int t = 0; t < 4; ++t)
#pragma unroll
            for (int r = 0; r < 4; ++r) {
                float aa = ge[t][r] * rcpf(1.0f + us[t][r]);
                s1[t] += aa;
                s2[t] = fmaf(aa, aa, s2[t]);
            }
        float S1 = (s1[0] + s1[1]) + (s1[2] + s1[3]);
        float S2 = (s2[0] + s2[1]) + (s2[2] + s2[3]);

        // cross-lane reduce: lanes l, l^16, l^32, l^48 share this pixel
        S1 += __shfl_xor(S1, 16); S1 += __shfl_xor(S1, 32);
        S2 += __shfl_xor(S2, 16); S2 += __shfl_xor(S2, 32);
        if (lane < 16)
            fcb[prow + pxb + i * 16 + ni0] = 1.0f - S2 * rcpf(S1 + 1e-5f);

        c0 = n0; c1 = n1;
        fx += fxstep;
    }
}

// Phase 2: weighted-variance sum -> scalar. One thread = one pixel, all 3
// channels (fcb read once; traffic fcb 2MB + original 6.3MB).
__global__ __launch_bounds__(256) void k_phase2(
    const float* __restrict__ original,  // [B,3,H,W]
    const float* __restrict__ fcb,       // [B, NPIX]
    float* __restrict__ out)
{
    const int pix = blockIdx.x * 256 + threadIdx.x;

    float f[NB];
    float tot = 0.f;
#pragma unroll
    for (int b = 0; b < NB; ++b) { f[b] = fcb[(size_t)b * NPIX + pix]; tot += f[b]; }

    float part = 0.f;
#pragma unroll
    for (int c = 0; c < 3; ++c) {
        float o[NB];
        float wm = 0.f;
#pragma unroll
        for (int b = 0; b < NB; ++b) {
            o[b] = original[((size_t)(b * 3 + c)) * NPIX + pix];
            wm = fmaf(o[b], f[b], wm);
        }
#pragma unroll
        for (int b = 0; b < NB; ++b) {
            float d = o[b] - wm;
            part = fmaf(d * d, f[b], part);
        }
    }
    part *= rcpf(tot);

#pragma unroll
    for (int off = 32; off > 0; off >>= 1) part += __shfl_down(part, off);
    __shared__ float sred[4];
    if ((threadIdx.x & 63) == 0) sred[threadIdx.x >> 6] = part;
    __syncthreads();
    if (threadIdx.x == 0) atomicAdd(out, sred[0] + sred[1] + sred[2] + sred[3]);
}

// Fallback: fully fused scalar path, only if ws_size too small (shouldn't happen).
__global__ __launch_bounds__(256) void k_fused(
    const float* __restrict__ original, const float* __restrict__ loc,
    const float* __restrict__ masks, const float* __restrict__ proto,
    const float* __restrict__ conf, float* __restrict__ out)
{
    const int pix = blockIdx.x * 256 + threadIdx.x;
    const float inv = 1.0f / 256.0f;
    const float fx = ((pix & 255) + 0.5f) * inv;
    const float fy = ((pix >> 8) + 0.5f) * inv;

    float f[NB];
    for (int b = 0; b < NB; ++b) {
        const float4* p4 = (const float4*)(proto + ((size_t)b * NPIX + pix) * KK);
        const float4* m4 = (const float4*)(masks + (size_t)b * NN * KK);
        const float4* l4 = (const float4*)(loc + (size_t)b * NN * 4);
        const float*  cf = conf + b * NN;
        float S1 = 0.f, S2 = 0.f;
        for (int n = 0; n < NN; ++n) {
            float sa = 0.f;
#pragma unroll
            for (int j = 0; j < 8; ++j) {
                float4 A = p4[j], m = m4[n * 8 + j];
                sa = fmaf(A.w, m.w, fmaf(A.z, m.z, fmaf(A.y, m.y, fmaf(A.x, m.x, sa))));
            }
            const float4 L = l4[n];
            float isx = rcpf(L.z), isy = rcpf(L.w);
            float dx = (fx - L.x) * isx, dy = (fy - L.y) * isy;
            float g = __expf(-0.5f * fmaf(dx, dx, dy * dy));
            float a = g * rcpf(1.0f + __expf(-sa)) * cf[n];
            S1 += a;
            S2 = fmaf(a, a, S2);
        }
        f[b] = 1.0f - S2 * rcpf(S1 + 1e-5f);
    }
    float tot = 0.f;
#pragma unroll
    for (int b = 0; b < NB; ++b) tot += f[b];
    float part = 0.f;
#pragma unroll
    for (int c = 0; c < 3; ++c) {
        float o[NB];
        float wm = 0.f;
#pragma unroll
        for (int b = 0; b < NB; ++b) {
            o[b] = original[((size_t)(b * 3 + c)) * NPIX + pix];
            wm = fmaf(o[b], f[b], wm);
        }
#pragma unroll
        for (int b = 0; b < NB; ++b) {
            float d = o[b] - wm;
            part = fmaf(d * d, f[b], part);
        }
    }
    part *= rcpf(tot);

#pragma unroll
    for (int off = 32; off > 0; off >>= 1) part += __shfl_down(part, off);
    __shared__ float sred[4];
    if ((threadIdx.x & 63) == 0) sred[threadIdx.x >> 6] = part;
    __syncthreads();
    if (threadIdx.x == 0) atomicAdd(out, sred[0] + sred[1] + sred[2] + sred[3]);
}

extern "C" void kernel_launch(void* const* d_in, const int* in_sizes, int n_in,
                              void* d_out, int out_size, void* d_ws, size_t ws_size,
                              hipStream_t stream) {
    const float* original = (const float*)d_in[0];
    const float* loc      = (const float*)d_in[1];
    const float* masks    = (const float*)d_in[2];
    const float* proto    = (const float*)d_in[3];
    const float* conf     = (const float*)d_in[4];
    float* out = (float*)d_out;

    const size_t fc_bytes = (size_t)NB * NPIX * sizeof(float);
    if (ws_size >= fc_bytes) {
        float* fcb = (float*)d_ws;
        k_phase1<<<NB * 128, 256, 0, stream>>>(loc, masks, proto, conf, fcb, out);
        k_phase2<<<NPIX / 256, 256, 0, stream>>>(original, fcb, out);
    } else {
        hipMemsetAsync(out, 0, sizeof(float), stream);
        k_fused<<<NPIX / 256, 256, 0, stream>>>(original, loc, masks, proto, conf, out);
    }
}